// Round 5
// baseline (333.057 us; speedup 1.0000x reference)
//
#include <hip/hip_runtime.h>

#define B_Q    1024
#define D_K    512
#define N_CLS  200
#define N_KEYS 50000
#define N_PAD  50048            // 391 * 128 (keys + pad rows)
#define N_ZT   (N_PAD / 128)    // 391: first z-tile index
#define NT_TOT (N_ZT + 2)       // 393 column tiles total
#define KN_ROWS 50304           // N_PAD + 256 (txt + zero tail)
#define RANK_BLKS 197           // ceil(KN_ROWS/256) rank blocks (scheduled first)

// prep row-range bounds (within prep portion of k_aux)
#define R0 N_PAD                // keys + pad rows -> kn (original order)
#define R1 (R0 + B_Q)           // img rows -> qn
#define R2 (R1 + N_CLS)         // txt rows -> kn tail
#define R3 (R2 + 56)            // zero kn tail rows
#define R4 (R3 + 400)           // zero d_out rows (400 * 2048B = 819200B)

typedef __attribute__((ext_vector_type(8))) short bf16x8;
typedef __attribute__((ext_vector_type(4))) float f32x4;

__device__ __forceinline__ unsigned short f2bf(float f) {
  union { float f; unsigned int i; } v; v.f = f;
  unsigned int r = v.i + 0x7fffu + ((v.i >> 16) & 1u);
  return (unsigned short)(r >> 16);
}
__device__ __forceinline__ uint4 pack8(const float f[8], float s) {
  uint4 o;
  o.x = (unsigned)f2bf(f[0]*s) | ((unsigned)f2bf(f[1]*s) << 16);
  o.y = (unsigned)f2bf(f[2]*s) | ((unsigned)f2bf(f[3]*s) << 16);
  o.z = (unsigned)f2bf(f[4]*s) | ((unsigned)f2bf(f[5]*s) << 16);
  o.w = (unsigned)f2bf(f[6]*s) | ((unsigned)f2bf(f[7]*s) << 16);
  return o;
}
__device__ __forceinline__ void async_copy16(const void* g, void* lds) {
  __builtin_amdgcn_global_load_lds(
      (const __attribute__((address_space(1))) unsigned int*)g,
      (__attribute__((address_space(3))) unsigned int*)lds, 16, 0, 0);
}

// ---- merged aux kernel (2 graph nodes total now). Blocks 0..RANK_BLKS-1 =
// ---- self-contained rank (scheduled FIRST so its LDS-atomic latency hides
// ---- under prep's BW streaming); remaining blocks = prep transform.
__global__ __launch_bounds__(256) void k_aux(const float* __restrict__ keys,
                                             const float* __restrict__ img,
                                             const float* __restrict__ txt,
                                             const int* __restrict__ labels,
                                             unsigned short* __restrict__ qn,
                                             unsigned short* __restrict__ kn,
                                             int* __restrict__ perm,
                                             int* __restrict__ cls,
                                             float* __restrict__ out) {
  if (blockIdx.x < RANK_BLKS) {
    // rank: each block scans ALL labels (L2-resident), builds hall = global
    // histogram, hbef = count before this block's 256-row chunk; scan hall ->
    // class starts; rank own rows via LDS counter. No global atomics, no
    // init kernel. Any within-class order is valid.
    __shared__ int hall[N_CLS];
    __shared__ int hbef[N_CLS];
    __shared__ int incl[N_CLS];
    __shared__ int lcur[N_CLS];
    int t = threadIdx.x;
    int base = blockIdx.x * 256;
    if (t < N_CLS) { hall[t] = 0; hbef[t] = 0; lcur[t] = 0; }
    __syncthreads();
    for (int idx = t; idx < N_KEYS; idx += 256) {
      int lab = labels[idx];
      atomicAdd(&hall[lab], 1);
      if (idx < base) atomicAdd(&hbef[lab], 1);
    }
    __syncthreads();
    if (t < N_CLS) incl[t] = hall[t];
    __syncthreads();
    for (int d = 1; d < N_CLS; d <<= 1) {          // inclusive scan of hall
      int x = 0;
      if (t < N_CLS && t >= d) x = incl[t - d];
      __syncthreads();
      if (t < N_CLS) incl[t] += x;
      __syncthreads();
    }
    int n = base + t;
    if (n < N_KEYS) {
      int lab = labels[n];
      int r = atomicAdd(&lcur[lab], 1);            // within-block rank (LDS)
      int d = (incl[lab] - hall[lab]) + hbef[lab] + r;
      perm[d] = n;
      cls[d] = lab;
    } else if (n < KN_ROWS) {
      perm[n] = n;                                 // pad / txt / zero-tail
      cls[n] = N_CLS;                              // sentinel
    }
    return;
  }
  // prep: keys(stream-read, normalize, LINEAR write) + img -> qn + txt ->
  // kn tail + zero pads + ZERO d_out. Pure transform (no atomics).
  int w = threadIdx.x >> 6, lane = threadIdx.x & 63;
  int row = (blockIdx.x - RANK_BLKS) * 4 + w;
  const float* src; unsigned short* dst;
  if (row < R0) {
    if (row >= N_KEYS) {  // pad row: zero
      *((uint4*)(kn + (size_t)row * D_K) + lane) = make_uint4(0, 0, 0, 0);
      return;
    }
    src = keys + (size_t)row * D_K;
    dst = kn + (size_t)row * D_K;        // original order; k_main gathers via perm
  } else if (row < R1) {
    int r = row - R0;
    src = img + (size_t)r * D_K;
    dst = qn + (size_t)r * D_K;
  } else if (row < R2) {
    int r = row - R1;
    src = txt + (size_t)r * D_K;
    dst = kn + (size_t)(N_PAD + r) * D_K;
  } else if (row < R3) {
    int r = N_PAD + N_CLS + (row - R2);   // zero tail kn rows
    *((uint4*)(kn + (size_t)r * D_K) + lane) = make_uint4(0, 0, 0, 0);
    return;
  } else if (row < R4) {
    int zr = row - R3;                    // zero 2 KB of d_out per wave
    uint4* o4 = (uint4*)(out + (size_t)zr * 512) + lane * 2;
    o4[0] = make_uint4(0, 0, 0, 0);
    o4[1] = make_uint4(0, 0, 0, 0);
    return;
  } else return;
  const float4* s4 = (const float4*)src + lane * 2;
  float4 a = s4[0], b = s4[1];
  float f[8] = {a.x, a.y, a.z, a.w, b.x, b.y, b.z, b.w};
  float ss = 0.f;
#pragma unroll
  for (int i = 0; i < 8; i++) ss += f[i] * f[i];
#pragma unroll
  for (int d = 1; d < 64; d <<= 1) ss += __shfl_xor(ss, d);
  float rinv = rsqrtf(ss);
  *((uint4*)dst + lane) = pack8(f, rinv);
}

// ------- main MFMA GEMM: BK=32 double-buffer at the SAME 32 KB LDS as the
// verified round-2 kernel (unbundles R3's {dbuf, 64KB} experiment: iso-
// occupancy, pipelined). One barrier per K-step; stage(next) issues before
// compute(cur) so the vmcnt(0) drain at the barrier lands after ~16 MFMAs
// have covered the L2 latency. Swizzle re-derived for 64 B row stride:
// f(row) = (row ^ (row>>2)) & 3 -> 2 lanes per 4-bank set per quarter-wave
// (same 2-sweep minimum as the verified 0-conflict BK=64 layout).
// Kept: XCD panel swizzle, perm-gather, (256,3) no-squeeze bounds.
__global__ __launch_bounds__(256, 3) void k_main(const unsigned short* __restrict__ qn,
                                                 const unsigned short* __restrict__ kn,
                                                 const int* __restrict__ cls,
                                                 const int* __restrict__ perm,
                                                 float* __restrict__ out) {
  __shared__ unsigned short As[2][128 * 32];
  __shared__ unsigned short Bs[2][128 * 32];
  int t = threadIdx.x;
  // bijective XCD swizzle: xcd = id%8 gets work ids [xcd*393, (xcd+1)*393)
  int wsw = (blockIdx.x & 7) * NT_TOT + (blockIdx.x >> 3);
  int tileN = wsw >> 3, tileB = wsw & 7;
  int rowB0 = tileB * 128, rowN0 = tileN * 128;

  f32x4 acc[4][4];
#pragma unroll
  for (int i = 0; i < 4; i++)
#pragma unroll
    for (int j = 0; j < 4; j++) acc[i][j] = (f32x4){0.f, 0.f, 0.f, 0.f};

  int lane = t & 63, w = t >> 6;
  int wr = (w >> 1) * 64, wc = (w & 1) * 64;
  int l15 = lane & 15, lq = lane >> 4;
  // staging: slot s = t + 256c -> row = s>>2 (c adds 64), col-group = s&3.
  // source col-group = (t&3) ^ f(row); f(row)=f(row+64) so one gsw serves both.
  const int r0 = t >> 2;
  const int fr = (r0 ^ (r0 >> 2)) & 3;
  const int gsw = ((t & 3) ^ fr) * 8;          // swizzled source col (shorts)

  // prefetch gather rows + epilogue class metadata (hidden under K-loop)
  int prow0 = perm[rowN0 + r0];
  int prow1 = perm[rowN0 + r0 + 64];
  int cj[4];
#pragma unroll
  for (int j = 0; j < 4; j++) cj[j] = cls[rowN0 + wc + 16 * j + l15];
  int cseg0 = cls[rowN0 + wc];
  int cseg1 = cls[rowN0 + wc + 63];

  auto stage = [&](int p, int k0) {
    async_copy16(qn + (size_t)(rowB0 + r0) * D_K + k0 + gsw,      &As[p][t * 8]);
    async_copy16(qn + (size_t)(rowB0 + r0 + 64) * D_K + k0 + gsw, &As[p][2048 + t * 8]);
    async_copy16(kn + (size_t)prow0 * D_K + k0 + gsw,             &Bs[p][t * 8]);
    async_copy16(kn + (size_t)prow1 * D_K + k0 + gsw,             &Bs[p][2048 + t * 8]);
  };
  auto compute = [&](int p) {
    bf16x8 af[4], bf[4];
#pragma unroll
    for (int i = 0; i < 4; i++) {
      int ra = wr + 16 * i + l15;
      af[i] = *(const bf16x8*)&As[p][ra * 32 + ((lq ^ ((ra ^ (ra >> 2)) & 3)) * 8)];
    }
#pragma unroll
    for (int j = 0; j < 4; j++) {
      int rb = wc + 16 * j + l15;
      bf[j] = *(const bf16x8*)&Bs[p][rb * 32 + ((lq ^ ((rb ^ (rb >> 2)) & 3)) * 8)];
    }
#pragma unroll
    for (int i = 0; i < 4; i++)
#pragma unroll
      for (int j = 0; j < 4; j++)
        acc[i][j] = __builtin_amdgcn_mfma_f32_16x16x32_bf16(af[i], bf[j], acc[i][j], 0, 0, 0);
  };

  stage(0, 0);
  __syncthreads();                   // buf0 ready
#pragma unroll
  for (int k0 = 32; k0 < D_K; k0 += 32) {
    int p = ((k0 >> 5) - 1) & 1;
    stage(p ^ 1, k0);                // prefetch next K-tile (in flight over compute)
    compute(p);
    __syncthreads();                 // drain: next buf ready; all done reading p
  }
  compute(1);                        // 16th K-tile (buffer 1), no prefetch

  if (tileN >= N_ZT) {
    // z-tile: out[row][col] += 0.5 * 100 * sim  (out pre-zeroed by k_aux)
#pragma unroll
    for (int i = 0; i < 4; i++)
#pragma unroll
      for (int j = 0; j < 4; j++) {
        int col = rowN0 + wc + 16 * j + l15 - N_PAD;
        if (col < N_CLS) {
#pragma unroll
          for (int r = 0; r < 4; r++) {
            int row = rowB0 + wr + 16 * i + lq * 4 + r;
            atomicAdd(out + (size_t)row * N_CLS + col, 50.0f * acc[i][j][r]);
          }
        }
      }
    return;
  }

  // c-tile: aff = exp(5*sim); segment-sum over sorted classes; atomicAdd 0.5*sum
#pragma unroll
  for (int i = 0; i < 4; i++)
#pragma unroll
    for (int j = 0; j < 4; j++)
#pragma unroll
      for (int r = 0; r < 4; r++) acc[i][j][r] = __expf(5.0f * acc[i][j][r]);

  for (int c = cseg0; c <= cseg1; c++) {
    if (c >= N_CLS) break;  // pad sentinel; all later cols are pad too
#pragma unroll
    for (int i = 0; i < 4; i++) {
      float s0 = 0.f, s1 = 0.f, s2 = 0.f, s3 = 0.f;
#pragma unroll
      for (int j = 0; j < 4; j++) {
        if (cj[j] == c) {
          s0 += acc[i][j][0]; s1 += acc[i][j][1];
          s2 += acc[i][j][2]; s3 += acc[i][j][3];
        }
      }
#pragma unroll
      for (int d = 1; d < 16; d <<= 1) {
        s0 += __shfl_xor(s0, d); s1 += __shfl_xor(s1, d);
        s2 += __shfl_xor(s2, d); s3 += __shfl_xor(s3, d);
      }
      if (l15 == 0) {
        int row = rowB0 + wr + 16 * i + lq * 4;
        float* o = out + (size_t)row * N_CLS + c;
        if (s0 != 0.f) atomicAdd(o + 0 * N_CLS, 0.5f * s0);
        if (s1 != 0.f) atomicAdd(o + 1 * N_CLS, 0.5f * s1);
        if (s2 != 0.f) atomicAdd(o + 2 * N_CLS, 0.5f * s2);
        if (s3 != 0.f) atomicAdd(o + 3 * N_CLS, 0.5f * s3);
      }
    }
  }
}

extern "C" void kernel_launch(void* const* d_in, const int* in_sizes, int n_in,
                              void* d_out, int out_size, void* d_ws, size_t ws_size,
                              hipStream_t stream) {
  (void)in_sizes; (void)n_in; (void)out_size; (void)ws_size;
  const float* img    = (const float*)d_in[0];
  const float* txt    = (const float*)d_in[1];
  const float* keys   = (const float*)d_in[2];
  const int*   labels = (const int*)d_in[3];
  float*       out    = (float*)d_out;

  char* ws = (char*)d_ws;
  // workspace layout (bytes)
  unsigned short* qn = (unsigned short*)(ws + 0);         // 1024*512*2   = 1,048,576
  unsigned short* kn = (unsigned short*)(ws + 1048576);   // 50304*512*2  = 51,511,296
  int*  perm = (int*)(ws + 52559872);                     // 50304*4 = 201,216
  int*  cls  = (int*)(ws + 52761088);                     // 50304*4 = 201,216

  // 2 graph nodes: aux (rank blocks first, then prep) + main
  k_aux<<<RANK_BLKS + (R4 + 3) / 4, 256, 0, stream>>>(keys, img, txt, labels,
                                                      qn, kn, perm, cls, out);
  k_main<<<dim3(8 * NT_TOT), 256, 0, stream>>>(qn, kn, cls, perm, out);
}

// Round 6
// 248.818 us; speedup vs baseline: 1.3386x; 1.3386x over previous
//
#include <hip/hip_runtime.h>

#define B_Q    1024
#define D_K    512
#define N_CLS  200
#define N_KEYS 50000
#define N_PAD  50048            // 391 * 128 (keys + pad rows)
#define N_ZT   (N_PAD / 128)    // 391: first z-tile index
#define NT_TOT (N_ZT + 2)       // 393 column tiles total
#define KN_ROWS 50304           // N_PAD + 256 (txt + zero tail)
#define HS     16               // counter stride: 16 ints = 64 B = 1 cacheline

// prep2 row-range bounds
#define R0 N_PAD                // keys + pad rows -> kn (original order)
#define R1 (R0 + B_Q)           // img rows -> qn
#define R2 (R1 + N_CLS)         // txt rows -> kn tail
#define R3 (R2 + 56)            // zero kn tail rows
#define R4 (R3 + 400)           // zero d_out rows (400 * 2048B = 819200B)

typedef __attribute__((ext_vector_type(8))) short bf16x8;
typedef __attribute__((ext_vector_type(4))) float f32x4;

__device__ __forceinline__ unsigned short f2bf(float f) {
  union { float f; unsigned int i; } v; v.f = f;
  unsigned int r = v.i + 0x7fffu + ((v.i >> 16) & 1u);
  return (unsigned short)(r >> 16);
}
__device__ __forceinline__ uint4 pack8(const float f[8], float s) {
  uint4 o;
  o.x = (unsigned)f2bf(f[0]*s) | ((unsigned)f2bf(f[1]*s) << 16);
  o.y = (unsigned)f2bf(f[2]*s) | ((unsigned)f2bf(f[3]*s) << 16);
  o.z = (unsigned)f2bf(f[4]*s) | ((unsigned)f2bf(f[5]*s) << 16);
  o.w = (unsigned)f2bf(f[6]*s) | ((unsigned)f2bf(f[7]*s) << 16);
  return o;
}
__device__ __forceinline__ void async_copy16(const void* g, void* lds) {
  __builtin_amdgcn_global_load_lds(
      (const __attribute__((address_space(1))) unsigned int*)g,
      (__attribute__((address_space(3))) unsigned int*)lds, 16, 0, 0);
}

// ---- zero the strided counters: hist[200*HS] + cnt[200*HS] = 6400 ints.
__global__ void k_zero(int* __restrict__ g) {
  int i = blockIdx.x * 1024 + threadIdx.x;
  if (i < 2 * N_CLS * HS) g[i] = 0;
}

// ---- hierarchical parallel rank (R3-verified, others=159.3 aux): per-block
// ---- (1024 thr) LDS histogram of its chunk, ONE cacheline-strided global
// ---- reservation atomic per (block, class) (~9.6k total), then within-block
// ---- ranks via LDS atomics. Any within-class order is valid.
__global__ __launch_bounds__(1024) void k_rank(const int* __restrict__ labels,
                                               const int* __restrict__ ghist,
                                               int* __restrict__ gcnt,
                                               int* __restrict__ perm,
                                               int* __restrict__ cls) {
  __shared__ int incl[N_CLS];
  __shared__ int histl[N_CLS];
  __shared__ int lhist[N_CLS];
  __shared__ int lbase[N_CLS];
  __shared__ int lcur[N_CLS];
  int t = threadIdx.x;
  if (t < N_CLS) {
    int h = ghist[t * HS];
    histl[t] = h; incl[t] = h; lhist[t] = 0;
  }
  __syncthreads();
  for (int d = 1; d < N_CLS; d <<= 1) {          // inclusive scan of ghist
    int x = 0;
    if (t < N_CLS && t >= d) x = incl[t - d];
    __syncthreads();
    if (t < N_CLS) incl[t] += x;
    __syncthreads();
  }
  int n = blockIdx.x * 1024 + t;
  int lab = -1;
  if (n < N_KEYS) {
    lab = labels[n];
    atomicAdd(&lhist[lab], 1);                   // local histogram (LDS)
  }
  __syncthreads();
  if (t < N_CLS && lhist[t] > 0) {               // one reservation per class
    lbase[t] = (incl[t] - histl[t]) + atomicAdd(&gcnt[t * HS], lhist[t]);
    lcur[t] = 0;
  }
  __syncthreads();
  if (n < N_KEYS) {
    int r = atomicAdd(&lcur[lab], 1);            // within-block rank (LDS)
    int d = lbase[lab] + r;
    perm[d] = n;
    cls[d] = lab;
  } else if (n < KN_ROWS) {
    perm[n] = n;                                 // pad / txt / zero-tail
    cls[n] = N_CLS;                              // sentinel
  }
}

// ---- fused prep: keys(stream-read, normalize, LINEAR write) + histogram +
// ---- img -> qn + txt -> kn tail + zero pads + ZERO d_out. No sort dep.
__global__ void k_prep2(const float* __restrict__ keys, const float* __restrict__ img,
                        const float* __restrict__ txt, const int* __restrict__ labels,
                        unsigned short* __restrict__ qn, unsigned short* __restrict__ kn,
                        int* __restrict__ ghist, float* __restrict__ out) {
  int w = threadIdx.x >> 6, lane = threadIdx.x & 63;
  int row = blockIdx.x * 4 + w;
  const float* src; unsigned short* dst;
  if (row < R0) {
    if (row >= N_KEYS) {  // pad row: zero
      *((uint4*)(kn + (size_t)row * D_K) + lane) = make_uint4(0, 0, 0, 0);
      return;
    }
    if (lane == 0) atomicAdd(&ghist[labels[row] * HS], 1);  // strided, no-return
    src = keys + (size_t)row * D_K;
    dst = kn + (size_t)row * D_K;        // original order; k_main gathers via perm
  } else if (row < R1) {
    int r = row - R0;
    src = img + (size_t)r * D_K;
    dst = qn + (size_t)r * D_K;
  } else if (row < R2) {
    int r = row - R1;
    src = txt + (size_t)r * D_K;
    dst = kn + (size_t)(N_PAD + r) * D_K;
  } else if (row < R3) {
    int r = N_PAD + N_CLS + (row - R2);   // zero tail kn rows
    *((uint4*)(kn + (size_t)r * D_K) + lane) = make_uint4(0, 0, 0, 0);
    return;
  } else if (row < R4) {
    int zr = row - R3;                    // zero 2 KB of d_out per wave
    uint4* o4 = (uint4*)(out + (size_t)zr * 512) + lane * 2;
    o4[0] = make_uint4(0, 0, 0, 0);
    o4[1] = make_uint4(0, 0, 0, 0);
    return;
  } else return;
  const float4* s4 = (const float4*)src + lane * 2;
  float4 a = s4[0], b = s4[1];
  float f[8] = {a.x, a.y, a.z, a.w, b.x, b.y, b.z, b.w};
  float ss = 0.f;
#pragma unroll
  for (int i = 0; i < 8; i++) ss += f[i] * f[i];
#pragma unroll
  for (int d = 1; d < 64; d <<= 1) ss += __shfl_xor(ss, d);
  float rinv = rsqrtf(ss);
  *((uint4*)dst + lane) = pack8(f, rinv);
}

// ------- main MFMA GEMM: EXACT verified 89.4 µs structure (R2/R4) — single
// 32 KB LDS buffer, two barriers per K-step, (256,3)/80-VGPR, 0 conflicts.
// Do NOT restructure: R3's 64KB dbuf (occupancy loss) and R5's BK=32 dbuf
// (wrong swizzle, 6.4M conflicts) both regressed. Kept: XCD panel swizzle
// (FETCH 203->30 MB), perm-gather, XOR source swizzle.
__global__ __launch_bounds__(256, 3) void k_main(const unsigned short* __restrict__ qn,
                                                 const unsigned short* __restrict__ kn,
                                                 const int* __restrict__ cls,
                                                 const int* __restrict__ perm,
                                                 float* __restrict__ out) {
  __shared__ unsigned short As[128 * 64];
  __shared__ unsigned short Bs[128 * 64];
  int t = threadIdx.x;
  // bijective XCD swizzle: xcd = id%8 gets work ids [xcd*393, (xcd+1)*393)
  int wsw = (blockIdx.x & 7) * NT_TOT + (blockIdx.x >> 3);
  int tileN = wsw >> 3, tileB = wsw & 7;
  int rowB0 = tileB * 128, rowN0 = tileN * 128;

  f32x4 acc[4][4];
#pragma unroll
  for (int i = 0; i < 4; i++)
#pragma unroll
    for (int j = 0; j < 4; j++) acc[i][j] = (f32x4){0.f, 0.f, 0.f, 0.f};

  int lane = t & 63, w = t >> 6;
  int wr = (w >> 1) * 64, wc = (w & 1) * 64;
  int l15 = lane & 15, lq = lane >> 4;
  const int rA = t >> 3;                       // 0..31: row within 32-row chunk
  const int gsw = ((t & 7) ^ (rA & 7)) * 8;    // swizzled source col (shorts)
  const int sw = l15 & 7;                      // un-swizzle key for frag reads

  // prefetch gather rows + epilogue class metadata (hidden under K-loop)
  int prow[4];
#pragma unroll
  for (int i = 0; i < 4; i++) prow[i] = perm[rowN0 + i * 32 + rA];
  int cj[4];
#pragma unroll
  for (int j = 0; j < 4; j++) cj[j] = cls[rowN0 + wc + 16 * j + l15];
  int cseg0 = cls[rowN0 + wc];
  int cseg1 = cls[rowN0 + wc + 63];

  for (int k0 = 0; k0 < D_K; k0 += 64) {
    __syncthreads();
#pragma unroll
    for (int i = 0; i < 4; i++) {
      int row = i * 32 + rA;
      async_copy16(qn + (size_t)(rowB0 + row) * D_K + k0 + gsw, &As[i * 2048 + t * 8]);
      async_copy16(kn + (size_t)prow[i] * D_K + k0 + gsw, &Bs[i * 2048 + t * 8]);
    }
    __syncthreads();
#pragma unroll
    for (int ks = 0; ks < 64; ks += 32) {
      bf16x8 af[4], bf[4];
#pragma unroll
      for (int i = 0; i < 4; i++)
        af[i] = *(const bf16x8*)&As[(wr + 16 * i + l15) * 64 + ((((ks >> 3) + lq) ^ sw) * 8)];
#pragma unroll
      for (int j = 0; j < 4; j++)
        bf[j] = *(const bf16x8*)&Bs[(wc + 16 * j + l15) * 64 + ((((ks >> 3) + lq) ^ sw) * 8)];
#pragma unroll
      for (int i = 0; i < 4; i++)
#pragma unroll
        for (int j = 0; j < 4; j++)
          acc[i][j] = __builtin_amdgcn_mfma_f32_16x16x32_bf16(af[i], bf[j], acc[i][j], 0, 0, 0);
    }
  }

  if (tileN >= N_ZT) {
    // z-tile: out[row][col] += 0.5 * 100 * sim  (out pre-zeroed by k_prep2)
#pragma unroll
    for (int i = 0; i < 4; i++)
#pragma unroll
      for (int j = 0; j < 4; j++) {
        int col = rowN0 + wc + 16 * j + l15 - N_PAD;
        if (col < N_CLS) {
#pragma unroll
          for (int r = 0; r < 4; r++) {
            int row = rowB0 + wr + 16 * i + lq * 4 + r;
            atomicAdd(out + (size_t)row * N_CLS + col, 50.0f * acc[i][j][r]);
          }
        }
      }
    return;
  }

  // c-tile: aff = exp(5*sim); segment-sum over sorted classes; atomicAdd 0.5*sum
#pragma unroll
  for (int i = 0; i < 4; i++)
#pragma unroll
    for (int j = 0; j < 4; j++)
#pragma unroll
      for (int r = 0; r < 4; r++) acc[i][j][r] = __expf(5.0f * acc[i][j][r]);

  for (int c = cseg0; c <= cseg1; c++) {
    if (c >= N_CLS) break;  // pad sentinel; all later cols are pad too
#pragma unroll
    for (int i = 0; i < 4; i++) {
      float s0 = 0.f, s1 = 0.f, s2 = 0.f, s3 = 0.f;
#pragma unroll
      for (int j = 0; j < 4; j++) {
        if (cj[j] == c) {
          s0 += acc[i][j][0]; s1 += acc[i][j][1];
          s2 += acc[i][j][2]; s3 += acc[i][j][3];
        }
      }
#pragma unroll
      for (int d = 1; d < 16; d <<= 1) {
        s0 += __shfl_xor(s0, d); s1 += __shfl_xor(s1, d);
        s2 += __shfl_xor(s2, d); s3 += __shfl_xor(s3, d);
      }
      if (l15 == 0) {
        int row = rowB0 + wr + 16 * i + lq * 4;
        float* o = out + (size_t)row * N_CLS + c;
        if (s0 != 0.f) atomicAdd(o + 0 * N_CLS, 0.5f * s0);
        if (s1 != 0.f) atomicAdd(o + 1 * N_CLS, 0.5f * s1);
        if (s2 != 0.f) atomicAdd(o + 2 * N_CLS, 0.5f * s2);
        if (s3 != 0.f) atomicAdd(o + 3 * N_CLS, 0.5f * s3);
      }
    }
  }
}

extern "C" void kernel_launch(void* const* d_in, const int* in_sizes, int n_in,
                              void* d_out, int out_size, void* d_ws, size_t ws_size,
                              hipStream_t stream) {
  (void)in_sizes; (void)n_in; (void)out_size; (void)ws_size;
  const float* img    = (const float*)d_in[0];
  const float* txt    = (const float*)d_in[1];
  const float* keys   = (const float*)d_in[2];
  const int*   labels = (const int*)d_in[3];
  float*       out    = (float*)d_out;

  char* ws = (char*)d_ws;
  // workspace layout (bytes)
  unsigned short* qn = (unsigned short*)(ws + 0);         // 1024*512*2   = 1,048,576
  unsigned short* kn = (unsigned short*)(ws + 1048576);   // 50304*512*2  = 51,511,296
  int*  perm = (int*)(ws + 52559872);                     // 50304*4 = 201,216
  int*  cls  = (int*)(ws + 52761088);                     // 50304*4 = 201,216
  int*  gz   = (int*)(ws + 52962304);                     // 6400*4: strided hist+cnt

  // 4 graph nodes: zero + prep2 + rank + main
  k_zero<<<7, 1024, 0, stream>>>(gz);
  k_prep2<<<(R4 + 3) / 4, 256, 0, stream>>>(keys, img, txt, labels, qn, kn, gz, out);
  k_rank<<<(KN_ROWS + 1023) / 1024, 1024, 0, stream>>>(labels, gz, gz + N_CLS * HS, perm, cls);
  k_main<<<dim3(8 * NT_TOT), 256, 0, stream>>>(qn, kn, cls, perm, out);
}